// Round 4
// baseline (186.091 us; speedup 1.0000x reference)
//
#include <hip/hip_runtime.h>

#define D 32

typedef float floatx4 __attribute__((ext_vector_type(4)));

__global__ __launch_bounds__(256, 4)
void gin_fused(const float* __restrict__ X,
               const float* __restrict__ W,
               const int* __restrict__ rp,
               const int* __restrict__ ci,
               float* __restrict__ out,
               int n) {
    __shared__ float Wl[D * D];

    int tid = threadIdx.x;
    {
        const float4* Wv = (const float4*)W;
        float4* Wlv = (float4*)Wl;
        Wlv[tid] = Wv[tid];
    }
    __syncthreads();

    int wave = tid >> 6;        // 0..3
    int lane = tid & 63;
    int row = blockIdx.x * 4 + wave;
    if (row >= n) return;

    int start = rp[row];
    int deg   = rp[row + 1] - start;

    int g = lane >> 3;          // edge sub-group 0..7
    int s = lane & 7;           // float4 slot 0..7

    floatx4 acc = {0.f, 0.f, 0.f, 0.f};

    for (int cb = 0; cb < deg; cb += 64) {
        int rem = deg - cb;                       // > 0
        // coalesced prefetch of up to 64 edge ids; clamp OOB lanes to last edge
        int li = cb + lane;
        li = (li < deg) ? li : (deg - 1);
        int myci = ci[start + li];

        floatx4 x[8]; float m[8];
        // Phase 1: issue all valid gather groups back-to-back (wave-uniform guards)
        #pragma unroll
        for (int it = 0; it < 8; ++it) {
            if (it * 8 < rem) {                   // wave-uniform: skip dead groups
                int l  = it * 8 + g;
                int lc = (l < rem) ? l : (rem - 1);   // clamp to real edge (dup segment)
                int c  = __shfl(myci, lc, 64);
                m[it]  = (l < rem) ? 1.f : 0.f;
                x[it]  = __builtin_nontemporal_load(
                            (const floatx4*)(X + (size_t)c * D) + s);
            }
        }
        // Phase 2: accumulate (waitcnts batch here, loads stayed in flight)
        #pragma unroll
        for (int it = 0; it < 8; ++it) {
            if (it * 8 < rem) {
                acc.x = fmaf(m[it], x[it].x, acc.x);
                acc.y = fmaf(m[it], x[it].y, acc.y);
                acc.z = fmaf(m[it], x[it].z, acc.z);
                acc.w = fmaf(m[it], x[it].w, acc.w);
            }
        }
    }

    // Reduce across the 8 edge groups (xor over g bits: 8, 16, 32)
    #pragma unroll
    for (int off = 8; off < 64; off <<= 1) {
        acc.x += __shfl_xor(acc.x, off, 64);
        acc.y += __shfl_xor(acc.y, off, 64);
        acc.z += __shfl_xor(acc.z, off, 64);
        acc.w += __shfl_xor(acc.w, off, 64);
    }
    // lane (g,s) now holds aggregated X_prime[row][4s .. 4s+3]

    // Epilogue: out[row][j] = sum_d agg[d] * W[d][j]
    int j = lane & 31;
    float o = 0.f;
    #pragma unroll
    for (int sg = 0; sg < 8; ++sg) {
        float ax = __shfl(acc.x, sg, 64);
        float ay = __shfl(acc.y, sg, 64);
        float az = __shfl(acc.z, sg, 64);
        float aw = __shfl(acc.w, sg, 64);
        int d = 4 * sg;
        o = fmaf(ax, Wl[(d    ) * D + j], o);
        o = fmaf(ay, Wl[(d + 1) * D + j], o);
        o = fmaf(az, Wl[(d + 2) * D + j], o);
        o = fmaf(aw, Wl[(d + 3) * D + j], o);
    }
    if (lane < 32) out[(size_t)row * D + j] = o;
}

extern "C" void kernel_launch(void* const* d_in, const int* in_sizes, int n_in,
                              void* d_out, int out_size, void* d_ws, size_t ws_size,
                              hipStream_t stream) {
    const float* X  = (const float*)d_in[0];
    const float* W  = (const float*)d_in[1];
    const int*   rp = (const int*)d_in[2];
    const int*   ci = (const int*)d_in[3];
    float* out = (float*)d_out;

    int n = in_sizes[2] - 1;            // N nodes
    int blocks = (n + 3) / 4;           // 4 rows (waves) per block
    hipLaunchKernelGGL(gin_fused, dim3(blocks), dim3(256), 0, stream,
                       X, W, rp, ci, out, n);
}

// Round 5
// 170.348 us; speedup vs baseline: 1.0924x; 1.0924x over previous
//
#include <hip/hip_runtime.h>

#define D 32

// ---- Kernel 0: fp32 X -> packed bf16 (RNE) into workspace -----------------
__global__ __launch_bounds__(256)
void cvt_bf16(const float* __restrict__ X, uint* __restrict__ Xb, int total8) {
    int i = blockIdx.x * blockDim.x + threadIdx.x;
    if (i >= total8) return;
    const float4* src = (const float4*)X;
    float4 a = src[2 * i], b = src[2 * i + 1];
    auto pack2 = [](float lo, float hi) -> uint {
        uint ul = __float_as_uint(lo), uh = __float_as_uint(hi);
        ul = (ul + 0x7FFFu + ((ul >> 16) & 1u)) >> 16;
        uh = (uh + 0x7FFFu + ((uh >> 16) & 1u)) & 0xFFFF0000u;
        return ul | uh;
    };
    uint4 o;
    o.x = pack2(a.x, a.y); o.y = pack2(a.z, a.w);
    o.z = pack2(b.x, b.y); o.w = pack2(b.z, b.w);
    ((uint4*)Xb)[i] = o;
}

// ---- Kernel 1 (main): bf16 gather-aggregate + fused MLP -------------------
__global__ __launch_bounds__(256, 4)
void gin_fused_bf16(const uint* __restrict__ Xb,   // N rows x 16 uints (32 bf16)
                    const float* __restrict__ W,
                    const int* __restrict__ rp,
                    const int* __restrict__ ci,
                    float* __restrict__ out,
                    int n) {
    __shared__ float Wl[D * D];
    int tid = threadIdx.x;
    {
        const float4* Wv = (const float4*)W;
        ((float4*)Wl)[tid] = Wv[tid];
    }
    __syncthreads();

    int wave = tid >> 6;
    int lane = tid & 63;
    int row = blockIdx.x * 4 + wave;
    if (row >= n) return;

    int start = rp[row];
    int deg   = rp[row + 1] - start;

    int g = lane >> 2;   // 16 edge groups per wave
    int s = lane & 3;    // uint4 slot: bf16 elements 8s .. 8s+7

    float acc[8] = {0.f, 0.f, 0.f, 0.f, 0.f, 0.f, 0.f, 0.f};

    for (int cb = 0; cb < deg; cb += 64) {
        int rem = deg - cb;
        int li = cb + lane;
        li = (li < deg) ? li : (deg - 1);
        int myci = ci[start + li];          // one coalesced prefetch of 64 ids

        uint4 x[4]; float m[4];
        #pragma unroll
        for (int it = 0; it < 4; ++it) {
            if (it * 16 < rem) {            // wave-uniform skip of dead groups
                int l  = it * 16 + g;
                int lc = (l < rem) ? l : (rem - 1);   // clamp: dup real edge
                int c  = __shfl(myci, lc, 64);
                m[it]  = (l < rem) ? 1.f : 0.f;
                x[it]  = ((const uint4*)Xb)[(size_t)c * 4 + s];  // 16B of 64B row
            }
        }
        #pragma unroll
        for (int it = 0; it < 4; ++it) {
            if (it * 16 < rem) {
                uint q[4] = {x[it].x, x[it].y, x[it].z, x[it].w};
                #pragma unroll
                for (int k = 0; k < 4; ++k) {
                    float lo = __uint_as_float(q[k] << 16);
                    float hi = __uint_as_float(q[k] & 0xFFFF0000u);
                    acc[2 * k]     = fmaf(m[it], lo, acc[2 * k]);
                    acc[2 * k + 1] = fmaf(m[it], hi, acc[2 * k + 1]);
                }
            }
        }
    }

    // Combine the 16 edge groups: xor-reduce over g bits (4, 8, 16, 32)
    #pragma unroll
    for (int off = 4; off < 64; off <<= 1) {
        #pragma unroll
        for (int k = 0; k < 8; ++k)
            acc[k] += __shfl_xor(acc[k], off, 64);
    }
    // lanes 0..3 (s) now hold aggregated X_prime[row][8s .. 8s+7]

    int j = lane & 31;
    float o = 0.f;
    #pragma unroll
    for (int ss = 0; ss < 4; ++ss) {
        #pragma unroll
        for (int k = 0; k < 8; ++k) {
            float a = __shfl(acc[k], ss, 64);
            o = fmaf(a, Wl[(8 * ss + k) * D + j], o);
        }
    }
    if (lane < 32) out[(size_t)row * D + j] = o;
}

// ---- Fallback (fp32 gather, R2 structure) if ws too small -----------------
__global__ __launch_bounds__(256, 4)
void gin_fused_f32(const float* __restrict__ X,
                   const float* __restrict__ W,
                   const int* __restrict__ rp,
                   const int* __restrict__ ci,
                   float* __restrict__ out,
                   int n) {
    __shared__ float Wl[D * D];
    int tid = threadIdx.x;
    {
        const float4* Wv = (const float4*)W;
        ((float4*)Wl)[tid] = Wv[tid];
    }
    __syncthreads();

    int wave = tid >> 6;
    int lane = tid & 63;
    int row = blockIdx.x * 4 + wave;
    if (row >= n) return;

    int start = rp[row];
    int deg   = rp[row + 1] - start;
    int g = lane >> 3, s = lane & 7;
    float4 acc = make_float4(0.f, 0.f, 0.f, 0.f);

    for (int cb = 0; cb < deg; cb += 64) {
        int rem = deg - cb;
        int li = cb + lane;
        li = (li < deg) ? li : (deg - 1);
        int myci = ci[start + li];
        float4 x[8]; float m[8];
        #pragma unroll
        for (int it = 0; it < 8; ++it) {
            if (it * 8 < rem) {
                int l  = it * 8 + g;
                int lc = (l < rem) ? l : (rem - 1);
                int c  = __shfl(myci, lc, 64);
                m[it]  = (l < rem) ? 1.f : 0.f;
                x[it]  = ((const float4*)(X + (size_t)c * D))[s];
            }
        }
        #pragma unroll
        for (int it = 0; it < 8; ++it) {
            if (it * 8 < rem) {
                acc.x = fmaf(m[it], x[it].x, acc.x);
                acc.y = fmaf(m[it], x[it].y, acc.y);
                acc.z = fmaf(m[it], x[it].z, acc.z);
                acc.w = fmaf(m[it], x[it].w, acc.w);
            }
        }
    }
    #pragma unroll
    for (int off = 8; off < 64; off <<= 1) {
        acc.x += __shfl_xor(acc.x, off, 64);
        acc.y += __shfl_xor(acc.y, off, 64);
        acc.z += __shfl_xor(acc.z, off, 64);
        acc.w += __shfl_xor(acc.w, off, 64);
    }
    int j = lane & 31;
    float o = 0.f;
    #pragma unroll
    for (int sg = 0; sg < 8; ++sg) {
        float ax = __shfl(acc.x, sg, 64);
        float ay = __shfl(acc.y, sg, 64);
        float az = __shfl(acc.z, sg, 64);
        float aw = __shfl(acc.w, sg, 64);
        int d = 4 * sg;
        o = fmaf(ax, Wl[(d    ) * D + j], o);
        o = fmaf(ay, Wl[(d + 1) * D + j], o);
        o = fmaf(az, Wl[(d + 2) * D + j], o);
        o = fmaf(aw, Wl[(d + 3) * D + j], o);
    }
    if (lane < 32) out[(size_t)row * D + j] = o;
}

extern "C" void kernel_launch(void* const* d_in, const int* in_sizes, int n_in,
                              void* d_out, int out_size, void* d_ws, size_t ws_size,
                              hipStream_t stream) {
    const float* X  = (const float*)d_in[0];
    const float* W  = (const float*)d_in[1];
    const int*   rp = (const int*)d_in[2];
    const int*   ci = (const int*)d_in[3];
    float* out = (float*)d_out;

    int n = in_sizes[2] - 1;                 // N nodes
    int nelem = in_sizes[0];                 // N * 32 floats
    size_t need = (size_t)nelem * 2;         // bf16 bytes
    int blocks = (n + 3) / 4;

    if (ws_size >= need) {
        uint* Xb = (uint*)d_ws;
        int total8 = nelem / 8;
        hipLaunchKernelGGL(cvt_bf16, dim3((total8 + 255) / 256), dim3(256), 0,
                           stream, X, Xb, total8);
        hipLaunchKernelGGL(gin_fused_bf16, dim3(blocks), dim3(256), 0, stream,
                           Xb, W, rp, ci, out, n);
    } else {
        hipLaunchKernelGGL(gin_fused_f32, dim3(blocks), dim3(256), 0, stream,
                           X, W, rp, ci, out, n);
    }
}